// Round 1
// baseline (927.675 us; speedup 1.0000x reference)
//
#include <hip/hip_runtime.h>

#define DIM 64
#define ICH 32
#define OCH 64
#define SPA (DIM*DIM*DIM)   // 262144

// ---------------- Kernel A: GAP partial sums ----------------
// grid 2048 = 64 (b,c) pairs * 32 chunks; each block sums 8192 floats.
__global__ __launch_bounds__(256) void pool_kernel(const float* __restrict__ x,
                                                   float* __restrict__ partial) {
    int bid = blockIdx.x;
    int pair = bid >> 5;    // b*32 + c
    int chunk = bid & 31;
    const float4* base = (const float4*)(x + (size_t)pair * SPA + (size_t)chunk * 8192);
    int tid = threadIdx.x;
    float s = 0.f;
#pragma unroll
    for (int k = 0; k < 8; ++k) {
        float4 v = base[k * 256 + tid];
        s += (v.x + v.y) + (v.z + v.w);
    }
#pragma unroll
    for (int off = 32; off > 0; off >>= 1) s += __shfl_down(s, off, 64);
    __shared__ float red[4];
    int lane = tid & 63, wv = tid >> 6;
    if (lane == 0) red[wv] = s;
    __syncthreads();
    if (tid == 0) partial[bid] = (red[0] + red[1]) + (red[2] + red[3]);
}

// ---------------- Kernel B: attention + effective spectral weights ----------------
// 1 block, 64 threads. pooled -> relu(W1) -> W2 -> softmax -> w_eff[2][27]
__global__ __launch_bounds__(64) void attn_kernel(const float* __restrict__ partial,
                                                  const float* __restrict__ w1,
                                                  const float* __restrict__ b1,
                                                  const float* __restrict__ w2,
                                                  const float* __restrict__ b2,
                                                  float* __restrict__ weff) {
    __shared__ float pl[64], hh[16], at[8];
    int t = threadIdx.x;
    // pooled mean: sum 32 partials per (b,c)
    {
        float s = 0.f;
#pragma unroll
        for (int k = 0; k < 32; ++k) s += partial[t * 32 + k];
        pl[t] = s * (1.0f / (float)SPA);
    }
    __syncthreads();
    if (t < 16) {   // h = relu(pooled @ w1^T + b1): b in {0,1}, j in 0..7
        int b = t >> 3, j = t & 7;
        float a = b1[j];
        for (int c = 0; c < 32; ++c) a += pl[b * 32 + c] * w1[j * 32 + c];
        hh[t] = a > 0.f ? a : 0.f;
    }
    __syncthreads();
    if (t < 8) {    // logits = h @ w2^T + b2: b in {0,1}, k in 0..3
        int b = t >> 2, k = t & 3;
        float a = b2[k];
        for (int j = 0; j < 8; ++j) a += hh[b * 8 + j] * w2[k * 8 + j];
        at[t] = a;
    }
    __syncthreads();
    if (t < 2) {    // softmax over 4 experts
        float l0 = at[t*4], l1 = at[t*4+1], l2 = at[t*4+2], l3 = at[t*4+3];
        float m = fmaxf(fmaxf(l0, l1), fmaxf(l2, l3));
        float e0 = expf(l0 - m), e1 = expf(l1 - m), e2 = expf(l2 - m), e3 = expf(l3 - m);
        float inv = 1.0f / (e0 + e1 + e2 + e3);
        at[t*4] = e0 * inv; at[t*4+1] = e1 * inv; at[t*4+2] = e2 * inv; at[t*4+3] = e3 * inv;
    }
    __syncthreads();
    if (t < 54) {   // w_eff[b][tap] = sum_k att[b,k] * mask_k[tap]
        int b = t / 27, m = t % 27;
        int z = m / 9, y = (m / 3) % 3, xx = m % 3;
        int n = (z > 0) + (y > 0) + (xx > 0);
        // masks (derived analytically from the quantile bands):
        // mask0: n<=1, mask1: n==2, mask2: n>=2, mask3: n==3
        float w = 0.f;
        w += at[b*4 + 0] * ((n <= 1) ? 1.f : 0.f);
        w += at[b*4 + 1] * ((n == 2) ? 1.f : 0.f);
        w += at[b*4 + 2] * ((n >= 2) ? 1.f : 0.f);
        w += at[b*4 + 3] * ((n == 3) ? 1.f : 0.f);
        weff[t] = w;
    }
}

// ---------------- Kernel C: effective spatial kernels via tiny IFFT ----------------
// K_eff[b][i][tap][o] = (1/27) * Re( sum_{z,y,x} w_eff[b][zyx] * F[o,i,z,y,x] * e^{+2pi i m/3} )
// grid 128 = (b,o); 256 threads cover i*27 = 864 outputs.
__global__ __launch_bounds__(256) void ifft_kernel(const float* __restrict__ freq,
                                                   const float* __restrict__ weff,
                                                   float* __restrict__ keff) {
    int bx = blockIdx.x;
    int b = bx >> 6, o = bx & 63;
    __shared__ float we[27];
    int tid = threadIdx.x;
    if (tid < 27) we[tid] = weff[b * 27 + tid];
    __syncthreads();
    for (int idx = tid; idx < 864; idx += 256) {
        int i = idx / 27, t = idx % 27;
        int d = t / 9, h = (t / 3) % 3, w = t % 3;
        float s = 0.f;
#pragma unroll
        for (int z = 0; z < 3; ++z)
#pragma unroll
            for (int y = 0; y < 3; ++y)
#pragma unroll
                for (int xk = 0; xk < 3; ++xk) {
                    int m = (d * z + h * y + w * xk) % 3;
                    // e^{2pi i m/3}: cos = {1,-0.5,-0.5}, sin = {0, +s3, -s3}
                    float cm = (m == 0) ? 1.0f : -0.5f;
                    float sm = (m == 0) ? 0.0f : ((m == 1) ? 0.8660254037844386f
                                                           : -0.8660254037844386f);
                    const float* f = freq + (size_t)((((o * 32 + i) * 3 + z) * 3 + y) * 3 + xk) * 2;
                    s += we[z * 9 + y * 3 + xk] * (f[0] * cm - f[1] * sm);
                }
        keff[((size_t)(b * 32 + i) * 27 + t) * 64 + o] = s * (1.0f / 27.0f);
    }
}

// ---------------- Kernel D: the fused conv ----------------
// spatial tile 32(W) x 8(H) x 4(D), o-tile 16, ic chunks of 4.
#define BW 32
#define BH 8
#define BD 4
#define OT 16
#define ICC 4

__global__ __launch_bounds__(256) void conv_kernel(const float* __restrict__ x,
                                                   const float* __restrict__ kw_,
                                                   const float* __restrict__ bias,
                                                   float* __restrict__ out) {
    __shared__ float xs[ICC][BD + 2][BH + 2][BW + 3];   // stride 35 (odd) to spread banks
    __shared__ float ks[ICC][27][OT];

    int bid = blockIdx.x;                 // 2048 = 2(w) * 8(h) * 16(d) * 4(oblk) * 2(b)
    int wblk = bid & 1;
    int hblk = (bid >> 1) & 7;
    int dblk = (bid >> 4) & 15;
    int oblk = (bid >> 8) & 3;
    int b    = bid >> 10;

    int tid = threadIdx.x;
    int tw = tid & 7, th = (tid >> 3) & 7, td = tid >> 6;
    int d0 = dblk * BD, h0 = hblk * BH, w0 = wblk * BW;

    float4 acc[OT];
#pragma unroll
    for (int i = 0; i < OT; ++i) acc[i] = make_float4(0.f, 0.f, 0.f, 0.f);

    for (int icc = 0; icc < ICH / ICC; ++icc) {
        __syncthreads();
        // ---- stage x tile (with halo, zero-padded at volume edges) ----
        for (int e = tid; e < ICC * (BD + 2) * (BH + 2) * (BW + 2); e += 256) {
            int ic = e / ((BD + 2) * (BH + 2) * (BW + 2));
            int r  = e % ((BD + 2) * (BH + 2) * (BW + 2));
            int zd = r / ((BH + 2) * (BW + 2));
            int r2 = r % ((BH + 2) * (BW + 2));
            int zh = r2 / (BW + 2);
            int zw = r2 % (BW + 2);
            int gd = d0 - 1 + zd, gh = h0 - 1 + zh, gw = w0 - 1 + zw;
            float v = 0.f;
            if ((unsigned)gd < 64u && (unsigned)gh < 64u && (unsigned)gw < 64u)
                v = x[(((size_t)(b * ICH + icc * ICC + ic) * DIM + gd) * DIM + gh) * DIM + gw];
            xs[ic][zd][zh][zw] = v;
        }
        // ---- stage K chunk ----
        for (int e = tid; e < ICC * 27 * OT; e += 256) {
            int ic = e / (27 * OT);
            int r  = e % (27 * OT);
            int t  = r / OT;
            int o  = r % OT;
            ks[ic][t][o] = kw_[((size_t)(b * ICH + icc * ICC + ic) * 27 + t) * 64 + oblk * OT + o];
        }
        __syncthreads();
        // ---- compute ----
        for (int ic = 0; ic < ICC; ++ic) {
#pragma unroll
            for (int kd = 0; kd < 3; ++kd) {
#pragma unroll
                for (int kh = 0; kh < 3; ++kh) {
                    const float* xr = &xs[ic][td + kd][th + kh][tw * 4];
                    float xv[6];
#pragma unroll
                    for (int j = 0; j < 6; ++j) xv[j] = xr[j];
#pragma unroll
                    for (int kw2 = 0; kw2 < 3; ++kw2) {
                        const float4* kr4 = (const float4*)&ks[ic][kd * 9 + kh * 3 + kw2][0];
#pragma unroll
                        for (int o4 = 0; o4 < 4; ++o4) {
                            float4 kq = kr4[o4];
#pragma unroll
                            for (int c = 0; c < 4; ++c) {
                                float kv = (c == 0) ? kq.x : (c == 1) ? kq.y : (c == 2) ? kq.z : kq.w;
                                int oo = o4 * 4 + c;
                                acc[oo].x += xv[kw2 + 0] * kv;
                                acc[oo].y += xv[kw2 + 1] * kv;
                                acc[oo].z += xv[kw2 + 2] * kv;
                                acc[oo].w += xv[kw2 + 3] * kv;
                            }
                        }
                    }
                }
            }
        }
    }
    // ---- epilogue: + bias, write float4 ----
#pragma unroll
    for (int oo = 0; oo < OT; ++oo) {
        int o = oblk * OT + oo;
        float bv = bias[o];
        float4 v = acc[oo];
        v.x += bv; v.y += bv; v.z += bv; v.w += bv;
        size_t oidx = ((((size_t)(b * OCH + o)) * DIM + (d0 + td)) * DIM + (h0 + th)) * DIM
                      + (size_t)(w0 + tw * 4);
        *(float4*)(out + oidx) = v;
    }
}

extern "C" void kernel_launch(void* const* d_in, const int* in_sizes, int n_in,
                              void* d_out, int out_size, void* d_ws, size_t ws_size,
                              hipStream_t stream) {
    const float* x    = (const float*)d_in[0];
    const float* freq = (const float*)d_in[1];
    const float* w1   = (const float*)d_in[2];
    const float* b1   = (const float*)d_in[3];
    const float* w2   = (const float*)d_in[4];
    const float* b2   = (const float*)d_in[5];
    const float* bias = (const float*)d_in[6];
    float* out = (float*)d_out;
    float* ws  = (float*)d_ws;

    float* partial = ws;            // 2048 floats
    float* weff    = ws + 2048;     // 54 floats
    float* keff    = ws + 2176;     // 2*32*27*64 = 110592 floats

    pool_kernel<<<2048, 256, 0, stream>>>(x, partial);
    attn_kernel<<<1, 64, 0, stream>>>(partial, w1, b1, w2, b2, weff);
    ifft_kernel<<<128, 256, 0, stream>>>(freq, weff, keff);
    conv_kernel<<<2048, 256, 0, stream>>>(x, keff, bias, out);
}

// Round 2
// 279.906 us; speedup vs baseline: 3.3142x; 3.3142x over previous
//
#include <hip/hip_runtime.h>

#define DIM 64
#define ICH 32
#define OCH 64
#define SPA (DIM*DIM*DIM)   // 262144

typedef short  s16x8  __attribute__((ext_vector_type(8)));
typedef float  f32x16 __attribute__((ext_vector_type(16)));

__device__ __forceinline__ short f2bf(float f) {   // fp32 -> bf16 bits, RNE
    unsigned u = __float_as_uint(f);
    return (short)((u + 0x7fffu + ((u >> 16) & 1u)) >> 16);
}
// LDS XOR swizzle (involution, applied to byte addresses on write AND read)
__device__ __forceinline__ int swz(int a) { return a ^ (((a >> 7) & 7) << 4); }

// ---------------- Kernel A: GAP partial sums ----------------
__global__ __launch_bounds__(256) void pool_kernel(const float* __restrict__ x,
                                                   float* __restrict__ partial) {
    int bid = blockIdx.x;
    int pair = bid >> 5;    // b*32 + c
    int chunk = bid & 31;
    const float4* base = (const float4*)(x + (size_t)pair * SPA + (size_t)chunk * 8192);
    int tid = threadIdx.x;
    float s = 0.f;
#pragma unroll
    for (int k = 0; k < 8; ++k) {
        float4 v = base[k * 256 + tid];
        s += (v.x + v.y) + (v.z + v.w);
    }
#pragma unroll
    for (int off = 32; off > 0; off >>= 1) s += __shfl_down(s, off, 64);
    __shared__ float red[4];
    int lane = tid & 63, wv = tid >> 6;
    if (lane == 0) red[wv] = s;
    __syncthreads();
    if (tid == 0) partial[bid] = (red[0] + red[1]) + (red[2] + red[3]);
}

// ---------------- Kernel B: attention -> w_eff[2][27] ----------------
__global__ __launch_bounds__(64) void attn_kernel(const float* __restrict__ partial,
                                                  const float* __restrict__ w1,
                                                  const float* __restrict__ b1,
                                                  const float* __restrict__ w2,
                                                  const float* __restrict__ b2,
                                                  float* __restrict__ weff) {
    __shared__ float pl[64], hh[16], at[8];
    int t = threadIdx.x;
    {
        float s = 0.f;
#pragma unroll
        for (int k = 0; k < 32; ++k) s += partial[t * 32 + k];
        pl[t] = s * (1.0f / (float)SPA);
    }
    __syncthreads();
    if (t < 16) {
        int b = t >> 3, j = t & 7;
        float a = b1[j];
        for (int c = 0; c < 32; ++c) a += pl[b * 32 + c] * w1[j * 32 + c];
        hh[t] = a > 0.f ? a : 0.f;
    }
    __syncthreads();
    if (t < 8) {
        int b = t >> 2, k = t & 3;
        float a = b2[k];
        for (int j = 0; j < 8; ++j) a += hh[b * 8 + j] * w2[k * 8 + j];
        at[t] = a;
    }
    __syncthreads();
    if (t < 2) {
        float l0 = at[t*4], l1 = at[t*4+1], l2 = at[t*4+2], l3 = at[t*4+3];
        float m = fmaxf(fmaxf(l0, l1), fmaxf(l2, l3));
        float e0 = expf(l0 - m), e1 = expf(l1 - m), e2 = expf(l2 - m), e3 = expf(l3 - m);
        float inv = 1.0f / (e0 + e1 + e2 + e3);
        at[t*4] = e0 * inv; at[t*4+1] = e1 * inv; at[t*4+2] = e2 * inv; at[t*4+3] = e3 * inv;
    }
    __syncthreads();
    if (t < 54) {
        int b = t / 27, m = t % 27;
        int z = m / 9, y = (m / 3) % 3, xx = m % 3;
        int n = (z > 0) + (y > 0) + (xx > 0);
        float w = 0.f;
        w += at[b*4 + 0] * ((n <= 1) ? 1.f : 0.f);
        w += at[b*4 + 1] * ((n == 2) ? 1.f : 0.f);
        w += at[b*4 + 2] * ((n >= 2) ? 1.f : 0.f);
        w += at[b*4 + 3] * ((n == 3) ? 1.f : 0.f);
        weff[t] = w;
    }
}

// ---------------- Kernel C: K_eff[b][tap][o][ic] in bf16 ----------------
// 110592 elements total = 432 blocks * 256 threads.
__global__ __launch_bounds__(256) void ifft_kernel(const float* __restrict__ freq,
                                                   const float* __restrict__ weff,
                                                   short* __restrict__ keff) {
    int idx = blockIdx.x * 256 + threadIdx.x;
    int i = idx & 31;
    int o = (idx >> 5) & 63;
    int bt = idx >> 11;          // b*27 + t, uniform per block
    int t = bt % 27, b = bt / 27;
    int d = t / 9, h = (t / 3) % 3, w = t % 3;
    const float* f = freq + (size_t)(o * 32 + i) * 54;
    float s = 0.f;
#pragma unroll
    for (int z = 0; z < 3; ++z)
#pragma unroll
        for (int y = 0; y < 3; ++y)
#pragma unroll
            for (int xk = 0; xk < 3; ++xk) {
                int m = (d * z + h * y + w * xk) % 3;
                float cm = (m == 0) ? 1.0f : -0.5f;
                float sm = (m == 0) ? 0.0f : ((m == 1) ? 0.8660254037844386f
                                                       : -0.8660254037844386f);
                int tap = z * 9 + y * 3 + xk;
                s += weff[b * 27 + tap] * (f[tap * 2] * cm - f[tap * 2 + 1] * sm);
            }
    keff[idx] = f2bf(s * (1.0f / 27.0f));
}

// ---------------- Kernel D: implicit-GEMM conv via bf16 MFMA ----------------
// Block: 64 o x (16w x 8h x 4d) spatial. 4 waves; wave w handles d-slice w,
// 64 o x 128 spatial (2 o-tiles x 4 sp-tiles of 32x32 MFMA).
// K = ic, chunked 2 x 16; taps (27) looped, A = K_eff from global, B from LDS.
__global__ __launch_bounds__(256, 2) void conv_mfma(const float* __restrict__ x,
                                                    const short* __restrict__ keff,
                                                    const float* __restrict__ bias,
                                                    float* __restrict__ out) {
    // LDS x-tile: [d=6][h=10][w=18][ic=16] bf16 = 34560 B, XOR-swizzled
    __shared__ char xs[34560];

    int bid = blockIdx.x;            // 1024 = 4(w) * 8(h) * 16(d) * 2(b)
    int wblk = bid & 3;
    int hblk = (bid >> 2) & 7;
    int dblk = (bid >> 5) & 15;
    int b    = bid >> 9;
    int d0 = dblk * 4, h0 = hblk * 8, w0 = wblk * 16;

    int tid = threadIdx.x;
    int l = tid & 63, td = tid >> 6;

    f32x16 acc[2][4];
#pragma unroll
    for (int i = 0; i < 2; ++i)
#pragma unroll
        for (int j = 0; j < 4; ++j) acc[i][j] = f32x16{};

    // lane-constant parts of addresses
    int laneB = td * 5760 + ((l >> 4) & 1) * 576 + (l & 15) * 32 + (l >> 5) * 16;
    const short* Abase = keff + (size_t)b * 55296 + (l & 31) * 32 + (l >> 5) * 8;
    int p0 = tid >> 1, half = tid & 1;

    for (int chunk = 0; chunk < 2; ++chunk) {
        __syncthreads();
        // ---- stage: gather-transpose x (fp32 -> bf16) into [point][ic16] ----
        const float* xc = x + (size_t)(b * ICH + chunk * 16 + half * 8) * SPA;
#pragma unroll
        for (int it = 0; it < 9; ++it) {
            int e = it * 256 + tid;
            if (e < 2160) {
                int p = it * 128 + p0;            // 0..1079
                int dd = p / 180, r = p - dd * 180;
                int hh2 = r / 18, ww2 = r - hh2 * 18;
                int gd = d0 - 1 + dd, gh = h0 - 1 + hh2, gw = w0 - 1 + ww2;
                s16x8 v = {};
                if ((unsigned)gd < 64u && (unsigned)gh < 64u && (unsigned)gw < 64u) {
                    const float* xp = xc + (((gd * 64) + gh) * 64 + gw);
#pragma unroll
                    for (int j = 0; j < 8; ++j) v[j] = f2bf(xp[(size_t)j * SPA]);
                }
                *(s16x8*)(xs + swz(e * 16)) = v;
            }
        }
        __syncthreads();

        // ---- compute: 27 taps, A prefetch distance 1 ----
        const short* A = Abase + chunk * 16;
        s16x8 a0 = *(const s16x8*)(A);
        s16x8 a1 = *(const s16x8*)(A + 1024);
#pragma unroll 1
        for (int tap = 0; tap < 27; ++tap) {
            int nxt = (tap < 26) ? tap + 1 : 26;
            s16x8 n0 = *(const s16x8*)(A + nxt * 2048);
            s16x8 n1 = *(const s16x8*)(A + nxt * 2048 + 1024);
            int kd = tap / 9, rr = tap - kd * 9;
            int kh = rr / 3, kw2 = rr - kh * 3;
            int off = laneB + kd * 5760 + kh * 576 + kw2 * 32;
            s16x8 B0 = *(const s16x8*)(xs + swz(off));
            s16x8 B1 = *(const s16x8*)(xs + swz(off + 1152));
            s16x8 B2 = *(const s16x8*)(xs + swz(off + 2304));
            s16x8 B3 = *(const s16x8*)(xs + swz(off + 3456));
            acc[0][0] = __builtin_amdgcn_mfma_f32_32x32x16_bf16(a0, B0, acc[0][0], 0, 0, 0);
            acc[1][0] = __builtin_amdgcn_mfma_f32_32x32x16_bf16(a1, B0, acc[1][0], 0, 0, 0);
            acc[0][1] = __builtin_amdgcn_mfma_f32_32x32x16_bf16(a0, B1, acc[0][1], 0, 0, 0);
            acc[1][1] = __builtin_amdgcn_mfma_f32_32x32x16_bf16(a1, B1, acc[1][1], 0, 0, 0);
            acc[0][2] = __builtin_amdgcn_mfma_f32_32x32x16_bf16(a0, B2, acc[0][2], 0, 0, 0);
            acc[1][2] = __builtin_amdgcn_mfma_f32_32x32x16_bf16(a1, B2, acc[1][2], 0, 0, 0);
            acc[0][3] = __builtin_amdgcn_mfma_f32_32x32x16_bf16(a0, B3, acc[0][3], 0, 0, 0);
            acc[1][3] = __builtin_amdgcn_mfma_f32_32x32x16_bf16(a1, B3, acc[1][3], 0, 0, 0);
            a0 = n0; a1 = n1;
        }
    }

    // ---- epilogue: bias + scattered fp32 stores (64B coalesced per 16 lanes) ----
    float bv[32];
#pragma unroll
    for (int ot = 0; ot < 2; ++ot)
#pragma unroll
        for (int reg = 0; reg < 16; ++reg)
            bv[ot * 16 + reg] = bias[ot * 32 + (reg & 3) + 8 * (reg >> 2) + 4 * (l >> 5)];

    int dd = d0 + td;
    int ww2 = w0 + (l & 15);
    int hbase = h0 + ((l >> 4) & 1);
#pragma unroll
    for (int ot = 0; ot < 2; ++ot)
#pragma unroll
        for (int s = 0; s < 4; ++s) {
#pragma unroll
            for (int reg = 0; reg < 16; ++reg) {
                int o = ot * 32 + (reg & 3) + 8 * (reg >> 2) + 4 * (l >> 5);
                size_t oidx = (((size_t)(b * OCH + o) * DIM + dd) * DIM
                               + (hbase + 2 * s)) * DIM + ww2;
                out[oidx] = acc[ot][s][reg] + bv[ot * 16 + reg];
            }
        }
}

extern "C" void kernel_launch(void* const* d_in, const int* in_sizes, int n_in,
                              void* d_out, int out_size, void* d_ws, size_t ws_size,
                              hipStream_t stream) {
    const float* x    = (const float*)d_in[0];
    const float* freq = (const float*)d_in[1];
    const float* w1   = (const float*)d_in[2];
    const float* b1   = (const float*)d_in[3];
    const float* w2   = (const float*)d_in[4];
    const float* b2   = (const float*)d_in[5];
    const float* bias = (const float*)d_in[6];
    float* out = (float*)d_out;
    float* ws  = (float*)d_ws;

    float* partial = ws;                       // 2048 f32
    float* weff    = ws + 2048;                // 54 f32 (+pad)
    short* keff    = (short*)(ws + 2048 + 64); // 110592 bf16, 16B-aligned

    pool_kernel<<<2048, 256, 0, stream>>>(x, partial);
    attn_kernel<<<1, 64, 0, stream>>>(partial, w1, b1, w2, b2, weff);
    ifft_kernel<<<432, 256, 0, stream>>>(freq, weff, keff);
    conv_mfma<<<1024, 256, 0, stream>>>(x, keff, bias, out);
}